// Round 8
// baseline (1874520.703 us; speedup 1.0000x reference)
//
#include <hip/hip_runtime.h>
#include <stdint.h>

typedef __attribute__((ext_vector_type(8))) short bf16x8;
typedef __attribute__((ext_vector_type(4))) float f32x4;
typedef unsigned short u16;
typedef unsigned int u32;
typedef unsigned long long u64;

#define DEV static __device__ __forceinline__

// Problem constants: B=64, S=256, C=12, Ec=50, Hc=64, Ew=300, Hw=320, Din=428, NT=20
// word count N = B*S = 16384. x rows are r = t*64 + b (time-major == packed order).

DEV u16 f2b(float f){ union{float f; u32 u;} v; v.f=f; return (u16)((v.u + 0x7FFFu + ((v.u>>16)&1u))>>16); }
DEV float b2f(u16 b){ union{u32 u; float f;} v; v.u=((u32)b)<<16; return v.f; }
DEV float sigm(float x){ return 1.0f/(1.0f + __expf(-x)); }
DEV float tanhf2(float x){ float a=fabsf(x); float e=__expf(-2.0f*a); float t=(1.0f-e)/(1.0f+e); return x<0.0f? -t : t; }

// Spin on a flag with per-poll L1 invalidate: each read sees XCD-L2 truth.
// (Without the in-loop buffer_inv, the first poll caches a stale line in the
// CU's vector L1 and the spin can never succeed -- R5/R6/R7 breakdown.)
DEV void spin_flag(const u32* fp, u32 tgt){
  int guard = 0;
  for (;;){
    u32 v;
    asm volatile("buffer_inv\n\tglobal_load_dword %0, %1, off sc0\n\ts_waitcnt vmcnt(0)"
                 : "=v"(v) : "v"(fp) : "memory");
    if (v >= tgt) break;
    __builtin_amdgcn_s_sleep(2);
    if (++guard > (1<<16)) break;   // tripwire: never triggers when protocol healthy
  }
}

// ---------------- flag init ----------------
__global__ void k_init(u32* flags){ flags[threadIdx.x] = 0u; }

// ---------------- char BiLSTM (fused emb-gather + input-proj + recurrence) ----------------
__global__ __launch_bounds__(256,1) void k_char(
    const int* __restrict__ char_ids, const float* __restrict__ cemb,
    const float* __restrict__ h0g, const float* __restrict__ c0g,
    const float* __restrict__ WihF, const float* __restrict__ WhhF,
    const float* __restrict__ bihF, const float* __restrict__ bhhF,
    const float* __restrict__ WihB, const float* __restrict__ WhhB,
    const float* __restrict__ bihB, const float* __restrict__ bhhB,
    u16* __restrict__ cfF, u16* __restrict__ cfB)
{
  __shared__ __align__(16) u16 Wl[256*128];  // swizzled [n][k]
  __shared__ __align__(16) u16 Xc[64*128];   // swizzled [word][k] = [emb(50)|h(64)|1|0pad]
  __shared__ __align__(16) u16 Gc[64*256];   // gates bf16

  const int dir = blockIdx.x & 1;
  const int n0  = (blockIdx.x >> 1) * 64;
  const int tid = threadIdx.x;
  const int lane = tid & 63, wv = tid >> 6;
  const int l15 = lane & 15, l4 = lane >> 4;

  const float* Wih = dir ? WihB : WihF;
  const float* Whh = dir ? WhhB : WhhF;
  const float* bih = dir ? bihB : bihF;
  const float* bhh = dir ? bhhB : bhhF;
  const float* h0 = h0g + dir*64;
  const float* c0 = c0g + dir*64;

  {
    const int n = tid; const int gt = n & 3, col = n >> 2;
    const int grow = gt*64 + col;
    for (int k = 0; k < 128; ++k){
      float v;
      if (k < 50) v = Wih[grow*50 + k];
      else if (k < 114) v = Whh[grow*64 + (k-50)];
      else if (k == 114) v = bih[grow] + bhh[grow];
      else v = 0.0f;
      Wl[n*128 + (k ^ ((n&7)<<3))] = f2b(v);
    }
  }
  for (int idx = tid; idx < 64*128; idx += 256){
    int w = idx >> 7, k = idx & 127;
    float v = (k==114) ? 1.0f : ((k>=50 && k<114) ? h0[k-50] : 0.0f);
    Xc[w*128 + (k ^ ((w&7)<<3))] = f2b(v);
  }
  const int uw = tid >> 2, ucb = (tid & 3) * 16;
  float cst[16], hreg[16];
  #pragma unroll
  for (int cc = 0; cc < 16; ++cc){ cst[cc] = c0[ucb + cc]; hreg[cc] = 0.0f; }

  for (int t = 0; t < 12; ++t){
    const int cpos = dir ? (11 - t) : t;
    __syncthreads();
    for (int idx = tid; idx < 3200; idx += 256){
      int w = idx / 50, k = idx - w*50;
      int cid = char_ids[(n0 + w)*12 + cpos];
      Xc[w*128 + (k ^ ((w&7)<<3))] = f2b(cemb[cid*50 + k]);
    }
    __syncthreads();
    f32x4 acc[4][4];
    #pragma unroll
    for (int mt=0; mt<4; ++mt)
      #pragma unroll
      for (int nt=0; nt<4; ++nt)
        #pragma unroll
        for (int j=0;j<4;++j) acc[mt][nt][j] = 0.0f;
    #pragma unroll
    for (int kk = 0; kk < 4; ++kk){
      bf16x8 A[4];
      #pragma unroll
      for (int mt=0; mt<4; ++mt){
        int row = mt*16 + l15;
        A[mt] = *(const bf16x8*)&Xc[row*128 + ((kk*32 + 8*l4) ^ ((row&7)<<3))];
      }
      #pragma unroll
      for (int nt=0; nt<4; ++nt){
        int n = wv*64 + nt*16 + l15;
        bf16x8 Bf = *(const bf16x8*)&Wl[n*128 + ((kk*32 + 8*l4) ^ ((n&7)<<3))];
        #pragma unroll
        for (int mt=0; mt<4; ++mt)
          acc[mt][nt] = __builtin_amdgcn_mfma_f32_16x16x32_bf16(A[mt], Bf, acc[mt][nt], 0,0,0);
      }
    }
    #pragma unroll
    for (int mt=0; mt<4; ++mt)
      #pragma unroll
      for (int nt=0; nt<4; ++nt)
        #pragma unroll
        for (int j=0;j<4;++j){
          int m = mt*16 + l4*4 + j;
          int n = wv*64 + nt*16 + l15;
          Gc[m*256 + n] = f2b(acc[mt][nt][j]);
        }
    __syncthreads();
    #pragma unroll
    for (int cc=0; cc<16; ++cc){
      int col = ucb + cc;
      const u16* gp = &Gc[uw*256 + col*4];
      float gi=b2f(gp[0]), gf=b2f(gp[1]), gg=b2f(gp[2]), go=b2f(gp[3]);
      float c2 = sigm(gf)*cst[cc] + sigm(gi)*tanhf2(gg);
      cst[cc]=c2;
      float h = sigm(go)*tanhf2(c2);
      hreg[cc]=h;
      Xc[uw*128 + ((50+col) ^ ((uw&7)<<3))] = f2b(h);
    }
  }
  u16* cf = dir ? cfB : cfF;
  #pragma unroll
  for (int cc=0; cc<16; ++cc) cf[(u64)(n0+uw)*64 + ucb + cc] = f2b(hreg[cc]);
}

// ---------------- build x [16384][448] bf16: [we(300)|cf_f(64)|cf_b(64)|1|0..] ----------------
__global__ __launch_bounds__(256,1) void k_buildx(
    const int* __restrict__ sents, const float* __restrict__ wemb,
    const u16* __restrict__ cfF, const u16* __restrict__ cfB,
    u16* __restrict__ xg)
{
  const int r = blockIdx.x*4 + (threadIdx.x >> 6);
  const int lane = threadIdx.x & 63;
  const int t = r >> 6, b = r & 63;
  const int sid = sents[b*256 + t];
  const int n = b*256 + t;                    // char word index (b-major)
  u32* xr = (u32*)(xg + (u64)r*448);
  const float* we = wemb + (u64)sid*300;
  const u16* cf = cfF + (u64)n*64;
  const u16* cb = cfB + (u64)n*64;
  for (int u = lane; u < 224; u += 64){
    int c0 = 2*u, c1 = 2*u + 1;
    u16 lo = (c0 < 300) ? f2b(we[c0]) : (c0 < 364) ? cf[c0-300] : (c0 < 428) ? cb[c0-364] : (c0==428) ? f2b(1.0f) : (u16)0;
    u16 hi = (c1 < 300) ? f2b(we[c1]) : (c1 < 364) ? cf[c1-300] : (c1 < 428) ? cb[c1-364] : (c1==428) ? f2b(1.0f) : (u16)0;
    xr[u] = (u32)lo | ((u32)hi << 16);
  }
}

// ---------------- shared helpers for word-LSTM input projection ----------------
DEV void stage_x(const u16* __restrict__ src, u16* Xs, int tid)
{
  #pragma unroll
  for (int half=0; half<2; ++half){
    f32x4 r[7];
    #pragma unroll
    for (int p=0;p<7;++p){ int idx=tid+256*(half*7+p); int row=idx/56, e=idx-row*56;
      r[p] = *(const f32x4*)(src + row*448 + e*8); }
    #pragma unroll
    for (int p=0;p<7;++p){ int idx=tid+256*(half*7+p); int row=idx/56, e=idx-row*56;
      *(f32x4*)&Xs[row*456 + e*8] = r[p]; }
  }
}

DEV void wih_mfma(f32x4 (&ACC)[2][4], const u16* Xs, const bf16x8 (&BWih)[2][14],
                  int l15, int l4)
{
  #pragma unroll
  for (int nt=0;nt<2;++nt)
    #pragma unroll
    for (int mt=0;mt<4;++mt)
      #pragma unroll
      for (int j=0;j<4;++j) ACC[nt][mt][j]=0.f;
  #pragma unroll
  for (int kk=0;kk<14;++kk){
    bf16x8 A[4];
    #pragma unroll
    for (int mt=0;mt<4;++mt)
      A[mt] = *(const bf16x8*)&Xs[(mt*16+l15)*456 + kk*32 + 8*l4];
    #pragma unroll
    for (int nt=0;nt<2;++nt)
      #pragma unroll
      for (int mt=0;mt<4;++mt)
        ACC[nt][mt] = __builtin_amdgcn_mfma_f32_16x16x32_bf16(A[mt], BWih[nt][kk], ACC[nt][mt],0,0,0);
  }
}

DEV void fill_bwih(bf16x8 (&BWih)[2][14], const float* Wih, const float* bih,
                   const float* bhh, int wg, int wv, int l15, int l4)
{
  #pragma unroll
  for (int nt=0; nt<2; ++nt){
    const int q = wv*32 + nt*16 + l15;
    const int col = q >> 2, gt = q & 3;
    const int grow = gt*320 + wg*32 + col;
    #pragma unroll
    for (int kk=0; kk<14; ++kk){
      bf16x8 v;
      #pragma unroll
      for (int j=0;j<8;++j){
        int k = kk*32 + 8*l4 + j;
        float f = (k < 428) ? Wih[(u64)grow*428 + k] : ((k==428) ? (bih[grow]+bhh[grow]) : 0.0f);
        v[j] = (short)f2b(f);
      }
      BWih[nt][kk] = v;
    }
  }
}

// ---------------- k_pre: G0[dir][t][wg][j][tid] = Wih·x + bias (f32 fragment layout) ----------------
// grid 640: bid = (dir*10 + wg)*32 + chunk, chunk covers 8 t's.
__global__ __launch_bounds__(256,1) void k_pre(
    const u16* __restrict__ xg,
    const float* __restrict__ WihFg, const float* __restrict__ bihFg, const float* __restrict__ bhhFg,
    const float* __restrict__ WihBg, const float* __restrict__ bihBg, const float* __restrict__ bhhBg,
    float* __restrict__ g0)
{
  __shared__ __align__(16) u16 Xs[64*456];
  const int bid = blockIdx.x;
  const int chunk = bid & 31;
  const int wgdir = bid >> 5;
  const int dir = wgdir / 10, wg = wgdir - dir*10;
  const int tid = threadIdx.x;
  const int lane = tid & 63, wv = tid >> 6;
  const int l15 = lane & 15, l4 = lane >> 4;

  const float* Wih = dir ? WihBg : WihFg;
  const float* bih = dir ? bihBg : bihFg;
  const float* bhh = dir ? bhhBg : bhhFg;

  bf16x8 BWih[2][14];
  fill_bwih(BWih, Wih, bih, bhh, wg, wv, l15, l4);

  f32x4 ACC[2][4];
  for (int tt=0; tt<8; ++tt){
    const int t = chunk*8 + tt;
    stage_x(xg + (u64)t*64*448, Xs, tid);
    __syncthreads();
    wih_mfma(ACC, Xs, BWih, l15, l4);
    float* gb = g0 + ((u64)((dir*256 + t)*10 + wg))*8192 + tid*4;
    #pragma unroll
    for (int nt=0; nt<2; ++nt)
      #pragma unroll
      for (int mt=0; mt<4; ++mt)
        *(f32x4*)(gb + (u64)(nt*4+mt)*1024) = ACC[nt][mt];
    __syncthreads();
  }
}

// ---------------- fast word BiLSTM: recurrence only; G0 loaded per step, added in f32 at EW ----------------
__global__ __launch_bounds__(256,1) void k_word_fast(
    const float* __restrict__ g0,
    const float* __restrict__ WhhFg, const float* __restrict__ WhhBg,
    u16* __restrict__ h_g, u32* __restrict__ flags, u16* __restrict__ hs)
{
  __shared__ __align__(16) u16 Hs[64*328];   // h stage, padded stride
  __shared__ int s_dir, s_wg;

  // --- XCD-clustered claim: fwd = first 10 WGs on XCD0, bwd = first 10 on XCD1 ---
  if (threadIdx.x == 0){
    u32 xcd;
    asm("s_getreg_b32 %0, hwreg(HW_REG_XCC_ID)" : "=s"(xcd));
    xcd &= 7u;
    int dir = -1, wg = 0;
    if (xcd <= 1u){
      u32 slot = atomicAdd(&flags[32 + xcd], 1u);
      if (slot < 10u){ dir = (int)xcd; wg = (int)slot; }
    }
    s_dir = dir; s_wg = wg;
  }
  __syncthreads();
  const int dir = s_dir, wg = s_wg;
  if (dir < 0) return;

  const int tid = threadIdx.x;
  const int lane = tid & 63, wv = tid >> 6;
  const int l15 = lane & 15, l4 = lane >> 4;
  const int qa = l15 & 3, qq = l15 >> 2;

  const float* Whh = dir ? WhhBg : WhhFg;

  // persistent Whh fragments. gate channel q = col*4 + gtype.
  bf16x8 BWhh[2][10];
  #pragma unroll
  for (int nt=0; nt<2; ++nt){
    const int q = wv*32 + nt*16 + l15;
    const int col = q >> 2, gt = q & 3;
    const int grow = gt*320 + wg*32 + col;
    #pragma unroll
    for (int kk=0; kk<10; ++kk){
      bf16x8 v;
      #pragma unroll
      for (int j=0;j<8;++j)
        v[j] = (short)f2b(Whh[(u64)grow*320 + kk*32 + 8*l4 + j]);
      BWhh[nt][kk] = v;
    }
  }

  float cst[8];
  #pragma unroll
  for (int p=0;p<8;++p) cst[p]=0.0f;

  for (int i=0; i<256; ++i){
    const int t = dir ? 255-i : i;
    const float* gb = g0 + ((u64)((dir*256 + t)*10 + wg))*8192 + tid*4;

    f32x4 ACC[2][4];
    #pragma unroll
    for (int nt=0;nt<2;++nt)
      #pragma unroll
      for (int mt=0;mt<4;++mt)
        #pragma unroll
        for (int j=0;j<4;++j) ACC[nt][mt][j]=0.f;
    f32x4 G0c[8];

    if (i > 0){
      // --- spin for all producers' step-i flags (in-loop L1 invalidate) ---
      if (tid < 10) spin_flag(&flags[dir*16 + tid], (u32)i);
      __syncthreads();
      asm volatile("buffer_inv" ::: "memory");   // fresh L1 for h reads
      // --- load h(i-1), stage to LDS ---
      {
        const u16* hb = h_g + (u64)(((i-1)&1)*2 + dir)*64*320;
        #pragma unroll
        for (int p=0; p<10; ++p){
          int idx = tid + 256*p;
          int row = idx / 40, e = idx - row*40;
          f32x4 v = *(const f32x4*)(hb + row*320 + e*8);
          *(f32x4*)&Hs[row*328 + e*8] = v;
        }
      }
      // --- issue G0(t) loads; they drain at the barrier alongside the h path ---
      #pragma unroll
      for (int j=0;j<8;++j) G0c[j] = *(const f32x4*)(gb + (u64)j*1024);
      __syncthreads();
      // --- Whh·h(i-1) accumulate (C starts at 0; G0 added in EW) ---
      #pragma unroll
      for (int kk=0; kk<10; ++kk){
        bf16x8 A[4];
        #pragma unroll
        for (int mt=0; mt<4; ++mt)
          A[mt] = *(const bf16x8*)&Hs[(mt*16 + l15)*328 + kk*32 + 8*l4];
        #pragma unroll
        for (int nt=0; nt<2; ++nt)
          #pragma unroll
          for (int mt=0; mt<4; ++mt)
            ACC[nt][mt] = __builtin_amdgcn_mfma_f32_16x16x32_bf16(A[mt], BWhh[nt][kk], ACC[nt][mt],0,0,0);
      }
    } else {
      #pragma unroll
      for (int j=0;j<8;++j) G0c[j] = *(const f32x4*)(gb + (u64)j*1024);
    }

    // --- EW: v = Whh·h + G0; in-register 4x4 transpose; bf16-round; gates; pack u64 ---
    u64 pk[2][4];
    #pragma unroll
    for (int nt=0; nt<2; ++nt){
      #pragma unroll
      for (int mt=0; mt<4; ++mt){
        f32x4 v = ACC[nt][mt] + G0c[nt*4 + mt];
        float t0=__shfl_xor(v[1],1), t1=__shfl_xor(v[0],1), t2=__shfl_xor(v[3],1), t3=__shfl_xor(v[2],1);
        v[0] = (qa&1) ? t0 : v[0];
        v[1] = (qa&1) ? v[1] : t1;
        v[2] = (qa&1) ? t2 : v[2];
        v[3] = (qa&1) ? v[3] : t3;
        float u0=__shfl_xor(v[2],2), u1=__shfl_xor(v[3],2), u2=__shfl_xor(v[0],2), u3=__shfl_xor(v[1],2);
        v[0] = (qa&2) ? u0 : v[0];
        v[1] = (qa&2) ? u1 : v[1];
        v[2] = (qa&2) ? v[2] : u2;
        v[3] = (qa&2) ? v[3] : u3;
        v[0]=b2f(f2b(v[0])); v[1]=b2f(f2b(v[1])); v[2]=b2f(f2b(v[2])); v[3]=b2f(f2b(v[3]));
        const int ci = nt*4 + mt;
        float c2 = sigm(v[1])*cst[ci] + sigm(v[0])*tanhf2(v[2]);
        cst[ci] = c2;
        float h = sigm(v[3])*tanhf2(c2);
        u32 hu = (u32)f2b(h);
        u32 v01 = hu | ((u32)__shfl_xor((int)hu, 4) << 16);
        u32 v23 = (u32)__shfl_xor((int)v01, 8);
        pk[nt][mt] = (u64)v01 | ((u64)v23 << 32);
      }
    }
    // --- h_g u64 stores (same-XCD L2), qq==0 lanes only ---
    {
      u16* hw = h_g + (u64)((i&1)*2 + dir)*64*320;
      if (qq == 0){
        #pragma unroll
        for (int nt=0; nt<2; ++nt)
          #pragma unroll
          for (int mt=0; mt<4; ++mt){
            const int b = mt*16 + l4*4 + qa;
            *(u64*)&hw[b*320 + wg*32 + wv*8 + nt*4] = pk[nt][mt];
          }
      }
    }
    // --- drain own stores, barrier, publish (plain sc0 store) ---
    asm volatile("s_waitcnt vmcnt(0)" ::: "memory");
    __syncthreads();
    if (tid == 0){
      u32 nv = (u32)(i+1);
      asm volatile("global_store_dword %0, %1, off sc0"
                   :: "v"(&flags[dir*16 + wg]), "v"(nv) : "memory");
    }
    // --- hs stores (consumed only by k_tag; off the critical path) ---
    if (qq == 0){
      #pragma unroll
      for (int nt=0; nt<2; ++nt)
        #pragma unroll
        for (int mt=0; mt<4; ++mt){
          const int b = mt*16 + l4*4 + qa;
          *(u64*)&hs[(u64)(t*64 + b)*640 + dir*320 + wg*32 + wv*8 + nt*4] = pk[nt][mt];
        }
    }
  }
}

// ---------------- slow word BiLSTM (fallback if ws too small) ----------------
__global__ __launch_bounds__(256,1) void k_word_slow(
    const u16* __restrict__ xg,
    const float* __restrict__ WihFg, const float* __restrict__ WhhFg,
    const float* __restrict__ bihFg, const float* __restrict__ bhhFg,
    const float* __restrict__ WihBg, const float* __restrict__ WhhBg,
    const float* __restrict__ bihBg, const float* __restrict__ bhhBg,
    u16* __restrict__ h_g, u32* __restrict__ flags, u16* __restrict__ hs)
{
  __shared__ __align__(16) u16 Hs[64*328];
  __shared__ __align__(16) u16 Xs[64*456];
  __shared__ int s_dir, s_wg;

  if (threadIdx.x == 0){
    u32 xcd;
    asm("s_getreg_b32 %0, hwreg(HW_REG_XCC_ID)" : "=s"(xcd));
    xcd &= 7u;
    int dir = -1, wg = 0;
    if (xcd <= 1u){
      u32 slot = atomicAdd(&flags[32 + xcd], 1u);
      if (slot < 10u){ dir = (int)xcd; wg = (int)slot; }
    }
    s_dir = dir; s_wg = wg;
  }
  __syncthreads();
  const int dir = s_dir, wg = s_wg;
  if (dir < 0) return;

  const int tid = threadIdx.x;
  const int lane = tid & 63, wv = tid >> 6;
  const int l15 = lane & 15, l4 = lane >> 4;
  const int qa = l15 & 3, qq = l15 >> 2;

  const float* Wih = dir ? WihBg : WihFg;
  const float* Whh = dir ? WhhBg : WhhFg;
  const float* bih = dir ? bihBg : bihFg;
  const float* bhh = dir ? bhhBg : bhhFg;

  bf16x8 BWih[2][14];
  fill_bwih(BWih, Wih, bih, bhh, wg, wv, l15, l4);
  bf16x8 BWhh[2][10];
  #pragma unroll
  for (int nt=0; nt<2; ++nt){
    const int q = wv*32 + nt*16 + l15;
    const int col = q >> 2, gt = q & 3;
    const int grow = gt*320 + wg*32 + col;
    #pragma unroll
    for (int kk=0; kk<10; ++kk){
      bf16x8 v;
      #pragma unroll
      for (int j=0;j<8;++j)
        v[j] = (short)f2b(Whh[(u64)grow*320 + kk*32 + 8*l4 + j]);
      BWhh[nt][kk] = v;
    }
  }

  float cst[8];
  #pragma unroll
  for (int p=0;p<8;++p) cst[p]=0.0f;

  f32x4 ACC[2][4];
  stage_x(xg + (u64)(dir ? 255 : 0)*64*448, Xs, tid);
  __syncthreads();
  wih_mfma(ACC, Xs, BWih, l15, l4);

  for (int i=0; i<256; ++i){
    const int t = dir ? 255-i : i;
    if (i > 0){
      if (tid < 10) spin_flag(&flags[dir*16 + tid], (u32)i);
      __syncthreads();
      asm volatile("buffer_inv" ::: "memory");
      {
        const u16* hb = h_g + (u64)(((i-1)&1)*2 + dir)*64*320;
        #pragma unroll
        for (int p=0; p<10; ++p){
          int idx = tid + 256*p;
          int row = idx / 40, e = idx - row*40;
          f32x4 v = *(const f32x4*)(hb + row*320 + e*8);
          *(f32x4*)&Hs[row*328 + e*8] = v;
        }
      }
      __syncthreads();
      #pragma unroll
      for (int kk=0; kk<10; ++kk){
        bf16x8 A[4];
        #pragma unroll
        for (int mt=0; mt<4; ++mt)
          A[mt] = *(const bf16x8*)&Hs[(mt*16 + l15)*328 + kk*32 + 8*l4];
        #pragma unroll
        for (int nt=0; nt<2; ++nt)
          #pragma unroll
          for (int mt=0; mt<4; ++mt)
            ACC[nt][mt] = __builtin_amdgcn_mfma_f32_16x16x32_bf16(A[mt], BWhh[nt][kk], ACC[nt][mt],0,0,0);
      }
    }

    u64 pk[2][4];
    #pragma unroll
    for (int nt=0; nt<2; ++nt){
      #pragma unroll
      for (int mt=0; mt<4; ++mt){
        f32x4 v = ACC[nt][mt];
        float t0=__shfl_xor(v[1],1), t1=__shfl_xor(v[0],1), t2=__shfl_xor(v[3],1), t3=__shfl_xor(v[2],1);
        v[0] = (qa&1) ? t0 : v[0];
        v[1] = (qa&1) ? v[1] : t1;
        v[2] = (qa&1) ? t2 : v[2];
        v[3] = (qa&1) ? v[3] : t3;
        float u0=__shfl_xor(v[2],2), u1=__shfl_xor(v[3],2), u2=__shfl_xor(v[0],2), u3=__shfl_xor(v[1],2);
        v[0] = (qa&2) ? u0 : v[0];
        v[1] = (qa&2) ? u1 : v[1];
        v[2] = (qa&2) ? v[2] : u2;
        v[3] = (qa&2) ? v[3] : u3;
        v[0]=b2f(f2b(v[0])); v[1]=b2f(f2b(v[1])); v[2]=b2f(f2b(v[2])); v[3]=b2f(f2b(v[3]));
        const int ci = nt*4 + mt;
        float c2 = sigm(v[1])*cst[ci] + sigm(v[0])*tanhf2(v[2]);
        cst[ci] = c2;
        float h = sigm(v[3])*tanhf2(c2);
        u32 hu = (u32)f2b(h);
        u32 v01 = hu | ((u32)__shfl_xor((int)hu, 4) << 16);
        u32 v23 = (u32)__shfl_xor((int)v01, 8);
        pk[nt][mt] = (u64)v01 | ((u64)v23 << 32);
      }
    }
    {
      u16* hw = h_g + (u64)((i&1)*2 + dir)*64*320;
      if (qq == 0){
        #pragma unroll
        for (int nt=0; nt<2; ++nt)
          #pragma unroll
          for (int mt=0; mt<4; ++mt){
            const int b = mt*16 + l4*4 + qa;
            *(u64*)&hw[b*320 + wg*32 + wv*8 + nt*4] = pk[nt][mt];
          }
      }
    }
    asm volatile("s_waitcnt vmcnt(0)" ::: "memory");
    __syncthreads();
    if (tid == 0){
      u32 nv = (u32)(i+1);
      asm volatile("global_store_dword %0, %1, off sc0"
                   :: "v"(&flags[dir*16 + wg]), "v"(nv) : "memory");
    }
    if (qq == 0){
      #pragma unroll
      for (int nt=0; nt<2; ++nt)
        #pragma unroll
        for (int mt=0; mt<4; ++mt){
          const int b = mt*16 + l4*4 + qa;
          *(u64*)&hs[(u64)(t*64 + b)*640 + dir*320 + wg*32 + wv*8 + nt*4] = pk[nt][mt];
        }
    }
    if (i < 255){
      stage_x(xg + (u64)(dir ? 254-i : i+1)*64*448, Xs, tid);
      __syncthreads();
      wih_mfma(ACC, Xs, BWih, l15, l4);
    }
  }
}

// ---------------- tag projection: [16384][640] @ W_tag.T + b_tag -> f32 out ----------------
__global__ __launch_bounds__(256,1) void k_tag(
    const u16* __restrict__ hs, const float* __restrict__ Wt,
    const float* __restrict__ bt, float* __restrict__ out)
{
  __shared__ __align__(16) u16 Wl[32*648];
  __shared__ float btl[32];
  const int tid = threadIdx.x;
  const int lane = tid & 63, wv = tid >> 6;
  const int l15 = lane & 15, l4 = lane >> 4;
  const int r0 = blockIdx.x * 64;

  for (int p=0; p<80; ++p){
    int idx = tid + 256*p;
    int nq = idx / 640, k = idx - nq*640;
    Wl[nq*648 + k] = (nq < 20) ? f2b(Wt[(u64)nq*640 + k]) : (u16)0;
  }
  if (tid < 32) btl[tid] = (tid < 20) ? bt[tid] : 0.0f;
  __syncthreads();

  f32x4 acc[2];
  #pragma unroll
  for (int nt=0;nt<2;++nt)
    #pragma unroll
    for (int j=0;j<4;++j) acc[nt][j]=0.0f;

  const int mrow = r0 + wv*16 + l15;
  #pragma unroll
  for (int kk=0; kk<20; ++kk){
    bf16x8 A = *(const bf16x8*)&hs[(u64)mrow*640 + kk*32 + 8*l4];
    #pragma unroll
    for (int nt=0; nt<2; ++nt){
      bf16x8 Bf = *(const bf16x8*)&Wl[(nt*16 + l15)*648 + kk*32 + 8*l4];
      acc[nt] = __builtin_amdgcn_mfma_f32_16x16x32_bf16(A, Bf, acc[nt], 0,0,0);
    }
  }
  #pragma unroll
  for (int nt=0; nt<2; ++nt){
    int nq = nt*16 + l15;
    if (nq < 20){
      #pragma unroll
      for (int j=0;j<4;++j){
        int row = r0 + wv*16 + l4*4 + j;
        out[(u64)row*20 + nq] = acc[nt][j] + btl[nq];
      }
    }
  }
}

extern "C" void kernel_launch(void* const* d_in, const int* in_sizes, int n_in,
                              void* d_out, int out_size, void* d_ws, size_t ws_size,
                              hipStream_t stream)
{
  (void)in_sizes; (void)n_in; (void)out_size;
  const int*   sents   = (const int*)d_in[0];
  const int*   charids = (const int*)d_in[2];
  const float* wemb    = (const float*)d_in[3];
  const float* cemb    = (const float*)d_in[4];
  const float* ch0     = (const float*)d_in[5];
  const float* cc0     = (const float*)d_in[6];
  const float* Wih_cf  = (const float*)d_in[7];
  const float* Whh_cf  = (const float*)d_in[8];
  const float* bih_cf  = (const float*)d_in[9];
  const float* bhh_cf  = (const float*)d_in[10];
  const float* Wih_cb  = (const float*)d_in[11];
  const float* Whh_cb  = (const float*)d_in[12];
  const float* bih_cb  = (const float*)d_in[13];
  const float* bhh_cb  = (const float*)d_in[14];
  const float* Wih_wf  = (const float*)d_in[15];
  const float* Whh_wf  = (const float*)d_in[16];
  const float* bih_wf  = (const float*)d_in[17];
  const float* bhh_wf  = (const float*)d_in[18];
  const float* Wih_wb  = (const float*)d_in[19];
  const float* Whh_wb  = (const float*)d_in[20];
  const float* bih_wb  = (const float*)d_in[21];
  const float* bhh_wb  = (const float*)d_in[22];
  const float* W_tag   = (const float*)d_in[23];
  const float* b_tag   = (const float*)d_in[24];

  // workspace layout (bytes)
  char* ws = (char*)d_ws;
  u32* flags = (u32*)(ws);                    //      256 B: [0..31] flags, [32..39] claim
  u16* h_g   = (u16*)(ws + 256);              //  163840 B
  u16* cf_f  = (u16*)(ws + 164096);           //  2.10 MB
  u16* cf_b  = (u16*)(ws + 2261248);          //  2.10 MB
  u16* x     = (u16*)(ws + 4358400);          // 14.68 MB
  u16* hs    = (u16*)(ws + 19038464);         // 20.97 MB: [16384][640] bf16
  float* g0  = (float*)(ws + 40009984);       // 167.77 MB: [dir][t][wg][j][tid] f32x4
  const u64 need = 40009984ull + 167772160ull;
  float* outp = (float*)d_out;

  hipLaunchKernelGGL(k_init, dim3(1), dim3(64), 0, stream, flags);
  hipLaunchKernelGGL(k_char, dim3(512), dim3(256), 0, stream,
    charids, cemb, ch0, cc0, Wih_cf, Whh_cf, bih_cf, bhh_cf,
    Wih_cb, Whh_cb, bih_cb, bhh_cb, cf_f, cf_b);
  hipLaunchKernelGGL(k_buildx, dim3(4096), dim3(256), 0, stream, sents, wemb, cf_f, cf_b, x);
  if ((u64)ws_size >= need){
    hipLaunchKernelGGL(k_pre, dim3(640), dim3(256), 0, stream,
      x, Wih_wf, bih_wf, bhh_wf, Wih_wb, bih_wb, bhh_wb, g0);
    hipLaunchKernelGGL(k_word_fast, dim3(256), dim3(256), 0, stream,
      g0, Whh_wf, Whh_wb, h_g, flags, hs);
  } else {
    hipLaunchKernelGGL(k_word_slow, dim3(256), dim3(256), 0, stream,
      x, Wih_wf, Whh_wf, bih_wf, bhh_wf, Wih_wb, Whh_wb, bih_wb, bhh_wb, h_g, flags, hs);
  }
  hipLaunchKernelGGL(k_tag, dim3(256), dim3(256), 0, stream, hs, W_tag, b_tag, outp);
}

// Round 9
// 1802.176 us; speedup vs baseline: 1040.1431x; 1040.1431x over previous
//
#include <hip/hip_runtime.h>
#include <stdint.h>

typedef __attribute__((ext_vector_type(8))) short bf16x8;
typedef __attribute__((ext_vector_type(4))) float f32x4;
typedef unsigned short u16;
typedef unsigned int u32;
typedef unsigned long long u64;

#define DEV static __device__ __forceinline__

// Problem constants: B=64, S=256, C=12, Ec=50, Hc=64, Ew=300, Hw=320, Din=428, NT=20
// word count N = B*S = 16384. x rows are r = t*64 + b (time-major == packed order).

DEV u16 f2b(float f){ union{float f; u32 u;} v; v.f=f; return (u16)((v.u + 0x7FFFu + ((v.u>>16)&1u))>>16); }
DEV float b2f(u16 b){ union{u32 u; float f;} v; v.u=((u32)b)<<16; return v.f; }
DEV float sigm(float x){ return 1.0f/(1.0f + __expf(-x)); }
DEV float tanhf2(float x){ float a=fabsf(x); float e=__expf(-2.0f*a); float t=(1.0f-e)/(1.0f+e); return x<0.0f? -t : t; }

// Producer/consumer sync via atomic RMW on BOTH sides: RMWs execute at the
// device coherence point, immune to L1 state / store buffering / per-XCD L2
// caching. (R5-R8 evidence: plain sc0-load polls NEVER observe a plain flag
// store unless the loop body has bulk post-publish traffic; consumer-side
// buffer_inv does not help.)
DEV void spin_flag(u32* fp, u32 tgt){
  int guard = 0;
  while (atomicAdd(fp, 0u) < tgt){
    __builtin_amdgcn_s_sleep(1);
    if (++guard > (1<<13)) break;   // tripwire: never triggers when protocol healthy
  }
}

// ---------------- flag init ----------------
__global__ void k_init(u32* flags){ flags[threadIdx.x] = 0u; }

// ---------------- char BiLSTM (fused emb-gather + input-proj + recurrence) ----------------
__global__ __launch_bounds__(256,1) void k_char(
    const int* __restrict__ char_ids, const float* __restrict__ cemb,
    const float* __restrict__ h0g, const float* __restrict__ c0g,
    const float* __restrict__ WihF, const float* __restrict__ WhhF,
    const float* __restrict__ bihF, const float* __restrict__ bhhF,
    const float* __restrict__ WihB, const float* __restrict__ WhhB,
    const float* __restrict__ bihB, const float* __restrict__ bhhB,
    u16* __restrict__ cfF, u16* __restrict__ cfB)
{
  __shared__ __align__(16) u16 Wl[256*128];  // swizzled [n][k]
  __shared__ __align__(16) u16 Xc[64*128];   // swizzled [word][k] = [emb(50)|h(64)|1|0pad]
  __shared__ __align__(16) u16 Gc[64*256];   // gates bf16

  const int dir = blockIdx.x & 1;
  const int n0  = (blockIdx.x >> 1) * 64;
  const int tid = threadIdx.x;
  const int lane = tid & 63, wv = tid >> 6;
  const int l15 = lane & 15, l4 = lane >> 4;

  const float* Wih = dir ? WihB : WihF;
  const float* Whh = dir ? WhhB : WhhF;
  const float* bih = dir ? bihB : bihF;
  const float* bhh = dir ? bhhB : bhhF;
  const float* h0 = h0g + dir*64;
  const float* c0 = c0g + dir*64;

  {
    const int n = tid; const int gt = n & 3, col = n >> 2;
    const int grow = gt*64 + col;
    for (int k = 0; k < 128; ++k){
      float v;
      if (k < 50) v = Wih[grow*50 + k];
      else if (k < 114) v = Whh[grow*64 + (k-50)];
      else if (k == 114) v = bih[grow] + bhh[grow];
      else v = 0.0f;
      Wl[n*128 + (k ^ ((n&7)<<3))] = f2b(v);
    }
  }
  for (int idx = tid; idx < 64*128; idx += 256){
    int w = idx >> 7, k = idx & 127;
    float v = (k==114) ? 1.0f : ((k>=50 && k<114) ? h0[k-50] : 0.0f);
    Xc[w*128 + (k ^ ((w&7)<<3))] = f2b(v);
  }
  const int uw = tid >> 2, ucb = (tid & 3) * 16;
  float cst[16], hreg[16];
  #pragma unroll
  for (int cc = 0; cc < 16; ++cc){ cst[cc] = c0[ucb + cc]; hreg[cc] = 0.0f; }

  for (int t = 0; t < 12; ++t){
    const int cpos = dir ? (11 - t) : t;
    __syncthreads();
    for (int idx = tid; idx < 3200; idx += 256){
      int w = idx / 50, k = idx - w*50;
      int cid = char_ids[(n0 + w)*12 + cpos];
      Xc[w*128 + (k ^ ((w&7)<<3))] = f2b(cemb[cid*50 + k]);
    }
    __syncthreads();
    f32x4 acc[4][4];
    #pragma unroll
    for (int mt=0; mt<4; ++mt)
      #pragma unroll
      for (int nt=0; nt<4; ++nt)
        #pragma unroll
        for (int j=0;j<4;++j) acc[mt][nt][j] = 0.0f;
    #pragma unroll
    for (int kk = 0; kk < 4; ++kk){
      bf16x8 A[4];
      #pragma unroll
      for (int mt=0; mt<4; ++mt){
        int row = mt*16 + l15;
        A[mt] = *(const bf16x8*)&Xc[row*128 + ((kk*32 + 8*l4) ^ ((row&7)<<3))];
      }
      #pragma unroll
      for (int nt=0; nt<4; ++nt){
        int n = wv*64 + nt*16 + l15;
        bf16x8 Bf = *(const bf16x8*)&Wl[n*128 + ((kk*32 + 8*l4) ^ ((n&7)<<3))];
        #pragma unroll
        for (int mt=0; mt<4; ++mt)
          acc[mt][nt] = __builtin_amdgcn_mfma_f32_16x16x32_bf16(A[mt], Bf, acc[mt][nt], 0,0,0);
      }
    }
    #pragma unroll
    for (int mt=0; mt<4; ++mt)
      #pragma unroll
      for (int nt=0; nt<4; ++nt)
        #pragma unroll
        for (int j=0;j<4;++j){
          int m = mt*16 + l4*4 + j;
          int n = wv*64 + nt*16 + l15;
          Gc[m*256 + n] = f2b(acc[mt][nt][j]);
        }
    __syncthreads();
    #pragma unroll
    for (int cc=0; cc<16; ++cc){
      int col = ucb + cc;
      const u16* gp = &Gc[uw*256 + col*4];
      float gi=b2f(gp[0]), gf=b2f(gp[1]), gg=b2f(gp[2]), go=b2f(gp[3]);
      float c2 = sigm(gf)*cst[cc] + sigm(gi)*tanhf2(gg);
      cst[cc]=c2;
      float h = sigm(go)*tanhf2(c2);
      hreg[cc]=h;
      Xc[uw*128 + ((50+col) ^ ((uw&7)<<3))] = f2b(h);
    }
  }
  u16* cf = dir ? cfB : cfF;
  #pragma unroll
  for (int cc=0; cc<16; ++cc) cf[(u64)(n0+uw)*64 + ucb + cc] = f2b(hreg[cc]);
}

// ---------------- build x [16384][448] bf16: [we(300)|cf_f(64)|cf_b(64)|1|0..] ----------------
__global__ __launch_bounds__(256,1) void k_buildx(
    const int* __restrict__ sents, const float* __restrict__ wemb,
    const u16* __restrict__ cfF, const u16* __restrict__ cfB,
    u16* __restrict__ xg)
{
  const int r = blockIdx.x*4 + (threadIdx.x >> 6);
  const int lane = threadIdx.x & 63;
  const int t = r >> 6, b = r & 63;
  const int sid = sents[b*256 + t];
  const int n = b*256 + t;                    // char word index (b-major)
  u32* xr = (u32*)(xg + (u64)r*448);
  const float* we = wemb + (u64)sid*300;
  const u16* cf = cfF + (u64)n*64;
  const u16* cb = cfB + (u64)n*64;
  for (int u = lane; u < 224; u += 64){
    int c0 = 2*u, c1 = 2*u + 1;
    u16 lo = (c0 < 300) ? f2b(we[c0]) : (c0 < 364) ? cf[c0-300] : (c0 < 428) ? cb[c0-364] : (c0==428) ? f2b(1.0f) : (u16)0;
    u16 hi = (c1 < 300) ? f2b(we[c1]) : (c1 < 364) ? cf[c1-300] : (c1 < 428) ? cb[c1-364] : (c1==428) ? f2b(1.0f) : (u16)0;
    xr[u] = (u32)lo | ((u32)hi << 16);
  }
}

// ---------------- shared helpers for word-LSTM input projection ----------------
DEV void stage_x(const u16* __restrict__ src, u16* Xs, int tid)
{
  #pragma unroll
  for (int half=0; half<2; ++half){
    f32x4 r[7];
    #pragma unroll
    for (int p=0;p<7;++p){ int idx=tid+256*(half*7+p); int row=idx/56, e=idx-row*56;
      r[p] = *(const f32x4*)(src + row*448 + e*8); }
    #pragma unroll
    for (int p=0;p<7;++p){ int idx=tid+256*(half*7+p); int row=idx/56, e=idx-row*56;
      *(f32x4*)&Xs[row*456 + e*8] = r[p]; }
  }
}

DEV void wih_mfma(f32x4 (&ACC)[2][4], const u16* Xs, const bf16x8 (&BWih)[2][14],
                  int l15, int l4)
{
  #pragma unroll
  for (int nt=0;nt<2;++nt)
    #pragma unroll
    for (int mt=0;mt<4;++mt)
      #pragma unroll
      for (int j=0;j<4;++j) ACC[nt][mt][j]=0.f;
  #pragma unroll
  for (int kk=0;kk<14;++kk){
    bf16x8 A[4];
    #pragma unroll
    for (int mt=0;mt<4;++mt)
      A[mt] = *(const bf16x8*)&Xs[(mt*16+l15)*456 + kk*32 + 8*l4];
    #pragma unroll
    for (int nt=0;nt<2;++nt)
      #pragma unroll
      for (int mt=0;mt<4;++mt)
        ACC[nt][mt] = __builtin_amdgcn_mfma_f32_16x16x32_bf16(A[mt], BWih[nt][kk], ACC[nt][mt],0,0,0);
  }
}

DEV void fill_bwih(bf16x8 (&BWih)[2][14], const float* Wih, const float* bih,
                   const float* bhh, int wg, int wv, int l15, int l4)
{
  #pragma unroll
  for (int nt=0; nt<2; ++nt){
    const int q = wv*32 + nt*16 + l15;
    const int col = q >> 2, gt = q & 3;
    const int grow = gt*320 + wg*32 + col;
    #pragma unroll
    for (int kk=0; kk<14; ++kk){
      bf16x8 v;
      #pragma unroll
      for (int j=0;j<8;++j){
        int k = kk*32 + 8*l4 + j;
        float f = (k < 428) ? Wih[(u64)grow*428 + k] : ((k==428) ? (bih[grow]+bhh[grow]) : 0.0f);
        v[j] = (short)f2b(f);
      }
      BWih[nt][kk] = v;
    }
  }
}

// ---------------- k_pre: G0[dir][t][wg][j][tid] = Wih·x + bias (f32 fragment layout) ----------------
// grid 640: bid = (dir*10 + wg)*32 + chunk, chunk covers 8 t's.
__global__ __launch_bounds__(256,1) void k_pre(
    const u16* __restrict__ xg,
    const float* __restrict__ WihFg, const float* __restrict__ bihFg, const float* __restrict__ bhhFg,
    const float* __restrict__ WihBg, const float* __restrict__ bihBg, const float* __restrict__ bhhBg,
    float* __restrict__ g0)
{
  __shared__ __align__(16) u16 Xs[64*456];
  const int bid = blockIdx.x;
  const int chunk = bid & 31;
  const int wgdir = bid >> 5;
  const int dir = wgdir / 10, wg = wgdir - dir*10;
  const int tid = threadIdx.x;
  const int lane = tid & 63, wv = tid >> 6;
  const int l15 = lane & 15, l4 = lane >> 4;

  const float* Wih = dir ? WihBg : WihFg;
  const float* bih = dir ? bihBg : bihFg;
  const float* bhh = dir ? bhhBg : bhhFg;

  bf16x8 BWih[2][14];
  fill_bwih(BWih, Wih, bih, bhh, wg, wv, l15, l4);

  f32x4 ACC[2][4];
  for (int tt=0; tt<8; ++tt){
    const int t = chunk*8 + tt;
    stage_x(xg + (u64)t*64*448, Xs, tid);
    __syncthreads();
    wih_mfma(ACC, Xs, BWih, l15, l4);
    float* gb = g0 + ((u64)((dir*256 + t)*10 + wg))*8192 + tid*4;
    #pragma unroll
    for (int nt=0; nt<2; ++nt)
      #pragma unroll
      for (int mt=0; mt<4; ++mt)
        *(f32x4*)(gb + (u64)(nt*4+mt)*1024) = ACC[nt][mt];
    __syncthreads();
  }
}

// ---------------- fast word BiLSTM: recurrence only; G0 loaded per step, added in f32 at EW ----------------
__global__ __launch_bounds__(256,1) void k_word_fast(
    const float* __restrict__ g0,
    const float* __restrict__ WhhFg, const float* __restrict__ WhhBg,
    u16* __restrict__ h_g, u32* __restrict__ flags, u16* __restrict__ hs)
{
  __shared__ __align__(16) u16 Hs[64*328];   // h stage, padded stride
  __shared__ int s_dir, s_wg;

  // --- XCD-clustered claim: fwd = first 10 WGs on XCD0, bwd = first 10 on XCD1 ---
  if (threadIdx.x == 0){
    u32 xcd;
    asm("s_getreg_b32 %0, hwreg(HW_REG_XCC_ID)" : "=s"(xcd));
    xcd &= 7u;
    int dir = -1, wg = 0;
    if (xcd <= 1u){
      u32 slot = atomicAdd(&flags[32 + xcd], 1u);
      if (slot < 10u){ dir = (int)xcd; wg = (int)slot; }
    }
    s_dir = dir; s_wg = wg;
  }
  __syncthreads();
  const int dir = s_dir, wg = s_wg;
  if (dir < 0) return;

  const int tid = threadIdx.x;
  const int lane = tid & 63, wv = tid >> 6;
  const int l15 = lane & 15, l4 = lane >> 4;
  const int qa = l15 & 3, qq = l15 >> 2;

  const float* Whh = dir ? WhhBg : WhhFg;

  // persistent Whh fragments. gate channel q = col*4 + gtype.
  bf16x8 BWhh[2][10];
  #pragma unroll
  for (int nt=0; nt<2; ++nt){
    const int q = wv*32 + nt*16 + l15;
    const int col = q >> 2, gt = q & 3;
    const int grow = gt*320 + wg*32 + col;
    #pragma unroll
    for (int kk=0; kk<10; ++kk){
      bf16x8 v;
      #pragma unroll
      for (int j=0;j<8;++j)
        v[j] = (short)f2b(Whh[(u64)grow*320 + kk*32 + 8*l4 + j]);
      BWhh[nt][kk] = v;
    }
  }

  float cst[8];
  #pragma unroll
  for (int p=0;p<8;++p) cst[p]=0.0f;

  for (int i=0; i<256; ++i){
    const int t = dir ? 255-i : i;
    const float* gb = g0 + ((u64)((dir*256 + t)*10 + wg))*8192 + tid*4;

    f32x4 ACC[2][4];
    #pragma unroll
    for (int nt=0;nt<2;++nt)
      #pragma unroll
      for (int mt=0;mt<4;++mt)
        #pragma unroll
        for (int j=0;j<4;++j) ACC[nt][mt][j]=0.f;
    f32x4 G0c[8];

    if (i > 0){
      // --- spin for all producers' step-i flags (atomic RMW poll) ---
      if (tid < 10) spin_flag(&flags[dir*16 + tid], (u32)i);
      __syncthreads();
      asm volatile("buffer_inv" ::: "memory");   // fresh L1 for h_g data reads
      // --- load h(i-1), stage to LDS ---
      {
        const u16* hb = h_g + (u64)(((i-1)&1)*2 + dir)*64*320;
        #pragma unroll
        for (int p=0; p<10; ++p){
          int idx = tid + 256*p;
          int row = idx / 40, e = idx - row*40;
          f32x4 v = *(const f32x4*)(hb + row*320 + e*8);
          *(f32x4*)&Hs[row*328 + e*8] = v;
        }
      }
      // --- issue G0(t) loads; they drain at the barrier alongside the h path ---
      #pragma unroll
      for (int j=0;j<8;++j) G0c[j] = *(const f32x4*)(gb + (u64)j*1024);
      __syncthreads();
      // --- Whh·h(i-1) accumulate (C starts at 0; G0 added in EW) ---
      #pragma unroll
      for (int kk=0; kk<10; ++kk){
        bf16x8 A[4];
        #pragma unroll
        for (int mt=0; mt<4; ++mt)
          A[mt] = *(const bf16x8*)&Hs[(mt*16 + l15)*328 + kk*32 + 8*l4];
        #pragma unroll
        for (int nt=0; nt<2; ++nt)
          #pragma unroll
          for (int mt=0; mt<4; ++mt)
            ACC[nt][mt] = __builtin_amdgcn_mfma_f32_16x16x32_bf16(A[mt], BWhh[nt][kk], ACC[nt][mt],0,0,0);
      }
    } else {
      #pragma unroll
      for (int j=0;j<8;++j) G0c[j] = *(const f32x4*)(gb + (u64)j*1024);
    }

    // --- EW: v = Whh·h + G0; in-register 4x4 transpose; bf16-round; gates; pack u64 ---
    u64 pk[2][4];
    #pragma unroll
    for (int nt=0; nt<2; ++nt){
      #pragma unroll
      for (int mt=0; mt<4; ++mt){
        f32x4 v = ACC[nt][mt] + G0c[nt*4 + mt];
        float t0=__shfl_xor(v[1],1), t1=__shfl_xor(v[0],1), t2=__shfl_xor(v[3],1), t3=__shfl_xor(v[2],1);
        v[0] = (qa&1) ? t0 : v[0];
        v[1] = (qa&1) ? v[1] : t1;
        v[2] = (qa&1) ? t2 : v[2];
        v[3] = (qa&1) ? v[3] : t3;
        float u0=__shfl_xor(v[2],2), u1=__shfl_xor(v[3],2), u2=__shfl_xor(v[0],2), u3=__shfl_xor(v[1],2);
        v[0] = (qa&2) ? u0 : v[0];
        v[1] = (qa&2) ? u1 : v[1];
        v[2] = (qa&2) ? v[2] : u2;
        v[3] = (qa&2) ? v[3] : u3;
        v[0]=b2f(f2b(v[0])); v[1]=b2f(f2b(v[1])); v[2]=b2f(f2b(v[2])); v[3]=b2f(f2b(v[3]));
        const int ci = nt*4 + mt;
        float c2 = sigm(v[1])*cst[ci] + sigm(v[0])*tanhf2(v[2]);
        cst[ci] = c2;
        float h = sigm(v[3])*tanhf2(c2);
        u32 hu = (u32)f2b(h);
        u32 v01 = hu | ((u32)__shfl_xor((int)hu, 4) << 16);
        u32 v23 = (u32)__shfl_xor((int)v01, 8);
        pk[nt][mt] = (u64)v01 | ((u64)v23 << 32);
      }
    }
    // --- h_g u64 stores (same-XCD L2), qq==0 lanes only ---
    {
      u16* hw = h_g + (u64)((i&1)*2 + dir)*64*320;
      if (qq == 0){
        #pragma unroll
        for (int nt=0; nt<2; ++nt)
          #pragma unroll
          for (int mt=0; mt<4; ++mt){
            const int b = mt*16 + l4*4 + qa;
            *(u64*)&hw[b*320 + wg*32 + wv*8 + nt*4] = pk[nt][mt];
          }
      }
    }
    // --- drain own stores, barrier, publish (atomic RMW) ---
    asm volatile("s_waitcnt vmcnt(0)" ::: "memory");
    __syncthreads();
    if (tid == 0) atomicExch(&flags[dir*16 + wg], (u32)(i+1));
    // --- hs stores (consumed only by k_tag; off the critical path) ---
    if (qq == 0){
      #pragma unroll
      for (int nt=0; nt<2; ++nt)
        #pragma unroll
        for (int mt=0; mt<4; ++mt){
          const int b = mt*16 + l4*4 + qa;
          *(u64*)&hs[(u64)(t*64 + b)*640 + dir*320 + wg*32 + wv*8 + nt*4] = pk[nt][mt];
        }
    }
  }
}

// ---------------- slow word BiLSTM (fallback if ws too small) ----------------
__global__ __launch_bounds__(256,1) void k_word_slow(
    const u16* __restrict__ xg,
    const float* __restrict__ WihFg, const float* __restrict__ WhhFg,
    const float* __restrict__ bihFg, const float* __restrict__ bhhFg,
    const float* __restrict__ WihBg, const float* __restrict__ WhhBg,
    const float* __restrict__ bihBg, const float* __restrict__ bhhBg,
    u16* __restrict__ h_g, u32* __restrict__ flags, u16* __restrict__ hs)
{
  __shared__ __align__(16) u16 Hs[64*328];
  __shared__ __align__(16) u16 Xs[64*456];
  __shared__ int s_dir, s_wg;

  if (threadIdx.x == 0){
    u32 xcd;
    asm("s_getreg_b32 %0, hwreg(HW_REG_XCC_ID)" : "=s"(xcd));
    xcd &= 7u;
    int dir = -1, wg = 0;
    if (xcd <= 1u){
      u32 slot = atomicAdd(&flags[32 + xcd], 1u);
      if (slot < 10u){ dir = (int)xcd; wg = (int)slot; }
    }
    s_dir = dir; s_wg = wg;
  }
  __syncthreads();
  const int dir = s_dir, wg = s_wg;
  if (dir < 0) return;

  const int tid = threadIdx.x;
  const int lane = tid & 63, wv = tid >> 6;
  const int l15 = lane & 15, l4 = lane >> 4;
  const int qa = l15 & 3, qq = l15 >> 2;

  const float* Wih = dir ? WihBg : WihFg;
  const float* Whh = dir ? WhhBg : WhhFg;
  const float* bih = dir ? bihBg : bihFg;
  const float* bhh = dir ? bhhBg : bhhFg;

  bf16x8 BWih[2][14];
  fill_bwih(BWih, Wih, bih, bhh, wg, wv, l15, l4);
  bf16x8 BWhh[2][10];
  #pragma unroll
  for (int nt=0; nt<2; ++nt){
    const int q = wv*32 + nt*16 + l15;
    const int col = q >> 2, gt = q & 3;
    const int grow = gt*320 + wg*32 + col;
    #pragma unroll
    for (int kk=0; kk<10; ++kk){
      bf16x8 v;
      #pragma unroll
      for (int j=0;j<8;++j)
        v[j] = (short)f2b(Whh[(u64)grow*320 + kk*32 + 8*l4 + j]);
      BWhh[nt][kk] = v;
    }
  }

  float cst[8];
  #pragma unroll
  for (int p=0;p<8;++p) cst[p]=0.0f;

  f32x4 ACC[2][4];
  stage_x(xg + (u64)(dir ? 255 : 0)*64*448, Xs, tid);
  __syncthreads();
  wih_mfma(ACC, Xs, BWih, l15, l4);

  for (int i=0; i<256; ++i){
    const int t = dir ? 255-i : i;
    if (i > 0){
      if (tid < 10) spin_flag(&flags[dir*16 + tid], (u32)i);
      __syncthreads();
      asm volatile("buffer_inv" ::: "memory");
      {
        const u16* hb = h_g + (u64)(((i-1)&1)*2 + dir)*64*320;
        #pragma unroll
        for (int p=0; p<10; ++p){
          int idx = tid + 256*p;
          int row = idx / 40, e = idx - row*40;
          f32x4 v = *(const f32x4*)(hb + row*320 + e*8);
          *(f32x4*)&Hs[row*328 + e*8] = v;
        }
      }
      __syncthreads();
      #pragma unroll
      for (int kk=0; kk<10; ++kk){
        bf16x8 A[4];
        #pragma unroll
        for (int mt=0; mt<4; ++mt)
          A[mt] = *(const bf16x8*)&Hs[(mt*16 + l15)*328 + kk*32 + 8*l4];
        #pragma unroll
        for (int nt=0; nt<2; ++nt)
          #pragma unroll
          for (int mt=0; mt<4; ++mt)
            ACC[nt][mt] = __builtin_amdgcn_mfma_f32_16x16x32_bf16(A[mt], BWhh[nt][kk], ACC[nt][mt],0,0,0);
      }
    }

    u64 pk[2][4];
    #pragma unroll
    for (int nt=0; nt<2; ++nt){
      #pragma unroll
      for (int mt=0; mt<4; ++mt){
        f32x4 v = ACC[nt][mt];
        float t0=__shfl_xor(v[1],1), t1=__shfl_xor(v[0],1), t2=__shfl_xor(v[3],1), t3=__shfl_xor(v[2],1);
        v[0] = (qa&1) ? t0 : v[0];
        v[1] = (qa&1) ? v[1] : t1;
        v[2] = (qa&1) ? t2 : v[2];
        v[3] = (qa&1) ? v[3] : t3;
        float u0=__shfl_xor(v[2],2), u1=__shfl_xor(v[3],2), u2=__shfl_xor(v[0],2), u3=__shfl_xor(v[1],2);
        v[0] = (qa&2) ? u0 : v[0];
        v[1] = (qa&2) ? u1 : v[1];
        v[2] = (qa&2) ? v[2] : u2;
        v[3] = (qa&2) ? v[3] : u3;
        v[0]=b2f(f2b(v[0])); v[1]=b2f(f2b(v[1])); v[2]=b2f(f2b(v[2])); v[3]=b2f(f2b(v[3]));
        const int ci = nt*4 + mt;
        float c2 = sigm(v[1])*cst[ci] + sigm(v[0])*tanhf2(v[2]);
        cst[ci] = c2;
        float h = sigm(v[3])*tanhf2(c2);
        u32 hu = (u32)f2b(h);
        u32 v01 = hu | ((u32)__shfl_xor((int)hu, 4) << 16);
        u32 v23 = (u32)__shfl_xor((int)v01, 8);
        pk[nt][mt] = (u64)v01 | ((u64)v23 << 32);
      }
    }
    {
      u16* hw = h_g + (u64)((i&1)*2 + dir)*64*320;
      if (qq == 0){
        #pragma unroll
        for (int nt=0; nt<2; ++nt)
          #pragma unroll
          for (int mt=0; mt<4; ++mt){
            const int b = mt*16 + l4*4 + qa;
            *(u64*)&hw[b*320 + wg*32 + wv*8 + nt*4] = pk[nt][mt];
          }
      }
    }
    asm volatile("s_waitcnt vmcnt(0)" ::: "memory");
    __syncthreads();
    if (tid == 0) atomicExch(&flags[dir*16 + wg], (u32)(i+1));
    if (qq == 0){
      #pragma unroll
      for (int nt=0; nt<2; ++nt)
        #pragma unroll
        for (int mt=0; mt<4; ++mt){
          const int b = mt*16 + l4*4 + qa;
          *(u64*)&hs[(u64)(t*64 + b)*640 + dir*320 + wg*32 + wv*8 + nt*4] = pk[nt][mt];
        }
    }
    if (i < 255){
      stage_x(xg + (u64)(dir ? 254-i : i+1)*64*448, Xs, tid);
      __syncthreads();
      wih_mfma(ACC, Xs, BWih, l15, l4);
    }
  }
}

// ---------------- tag projection: [16384][640] @ W_tag.T + b_tag -> f32 out ----------------
__global__ __launch_bounds__(256,1) void k_tag(
    const u16* __restrict__ hs, const float* __restrict__ Wt,
    const float* __restrict__ bt, float* __restrict__ out)
{
  __shared__ __align__(16) u16 Wl[32*648];
  __shared__ float btl[32];
  const int tid = threadIdx.x;
  const int lane = tid & 63, wv = tid >> 6;
  const int l15 = lane & 15, l4 = lane >> 4;
  const int r0 = blockIdx.x * 64;

  for (int p=0; p<80; ++p){
    int idx = tid + 256*p;
    int nq = idx / 640, k = idx - nq*640;
    Wl[nq*648 + k] = (nq < 20) ? f2b(Wt[(u64)nq*640 + k]) : (u16)0;
  }
  if (tid < 32) btl[tid] = (tid < 20) ? bt[tid] : 0.0f;
  __syncthreads();

  f32x4 acc[2];
  #pragma unroll
  for (int nt=0;nt<2;++nt)
    #pragma unroll
    for (int j=0;j<4;++j) acc[nt][j]=0.0f;

  const int mrow = r0 + wv*16 + l15;
  #pragma unroll
  for (int kk=0; kk<20; ++kk){
    bf16x8 A = *(const bf16x8*)&hs[(u64)mrow*640 + kk*32 + 8*l4];
    #pragma unroll
    for (int nt=0; nt<2; ++nt){
      bf16x8 Bf = *(const bf16x8*)&Wl[(nt*16 + l15)*648 + kk*32 + 8*l4];
      acc[nt] = __builtin_amdgcn_mfma_f32_16x16x32_bf16(A, Bf, acc[nt], 0,0,0);
    }
  }
  #pragma unroll
  for (int nt=0; nt<2; ++nt){
    int nq = nt*16 + l15;
    if (nq < 20){
      #pragma unroll
      for (int j=0;j<4;++j){
        int row = r0 + wv*16 + l4*4 + j;
        out[(u64)row*20 + nq] = acc[nt][j] + btl[nq];
      }
    }
  }
}

extern "C" void kernel_launch(void* const* d_in, const int* in_sizes, int n_in,
                              void* d_out, int out_size, void* d_ws, size_t ws_size,
                              hipStream_t stream)
{
  (void)in_sizes; (void)n_in; (void)out_size;
  const int*   sents   = (const int*)d_in[0];
  const int*   charids = (const int*)d_in[2];
  const float* wemb    = (const float*)d_in[3];
  const float* cemb    = (const float*)d_in[4];
  const float* ch0     = (const float*)d_in[5];
  const float* cc0     = (const float*)d_in[6];
  const float* Wih_cf  = (const float*)d_in[7];
  const float* Whh_cf  = (const float*)d_in[8];
  const float* bih_cf  = (const float*)d_in[9];
  const float* bhh_cf  = (const float*)d_in[10];
  const float* Wih_cb  = (const float*)d_in[11];
  const float* Whh_cb  = (const float*)d_in[12];
  const float* bih_cb  = (const float*)d_in[13];
  const float* bhh_cb  = (const float*)d_in[14];
  const float* Wih_wf  = (const float*)d_in[15];
  const float* Whh_wf  = (const float*)d_in[16];
  const float* bih_wf  = (const float*)d_in[17];
  const float* bhh_wf  = (const float*)d_in[18];
  const float* Wih_wb  = (const float*)d_in[19];
  const float* Whh_wb  = (const float*)d_in[20];
  const float* bih_wb  = (const float*)d_in[21];
  const float* bhh_wb  = (const float*)d_in[22];
  const float* W_tag   = (const float*)d_in[23];
  const float* b_tag   = (const float*)d_in[24];

  // workspace layout (bytes)
  char* ws = (char*)d_ws;
  u32* flags = (u32*)(ws);                    //      256 B: [0..31] flags, [32..39] claim
  u16* h_g   = (u16*)(ws + 256);              //  163840 B
  u16* cf_f  = (u16*)(ws + 164096);           //  2.10 MB
  u16* cf_b  = (u16*)(ws + 2261248);          //  2.10 MB
  u16* x     = (u16*)(ws + 4358400);          // 14.68 MB
  u16* hs    = (u16*)(ws + 19038464);         // 20.97 MB: [16384][640] bf16
  float* g0  = (float*)(ws + 40009984);       // 167.77 MB: [dir][t][wg][j][tid] f32x4
  const u64 need = 40009984ull + 167772160ull;
  float* outp = (float*)d_out;

  hipLaunchKernelGGL(k_init, dim3(1), dim3(64), 0, stream, flags);
  hipLaunchKernelGGL(k_char, dim3(512), dim3(256), 0, stream,
    charids, cemb, ch0, cc0, Wih_cf, Whh_cf, bih_cf, bhh_cf,
    Wih_cb, Whh_cb, bih_cb, bhh_cb, cf_f, cf_b);
  hipLaunchKernelGGL(k_buildx, dim3(4096), dim3(256), 0, stream, sents, wemb, cf_f, cf_b, x);
  if ((u64)ws_size >= need){
    hipLaunchKernelGGL(k_pre, dim3(640), dim3(256), 0, stream,
      x, Wih_wf, bih_wf, bhh_wf, Wih_wb, bih_wb, bhh_wb, g0);
    hipLaunchKernelGGL(k_word_fast, dim3(256), dim3(256), 0, stream,
      g0, Whh_wf, Whh_wb, h_g, flags, hs);
  } else {
    hipLaunchKernelGGL(k_word_slow, dim3(256), dim3(256), 0, stream,
      x, Wih_wf, Whh_wf, bih_wf, bhh_wf, Wih_wb, Whh_wb, bih_wb, bhh_wb, h_g, flags, hs);
  }
  hipLaunchKernelGGL(k_tag, dim3(256), dim3(256), 0, stream, hs, W_tag, b_tag, outp);
}